// Round 4
// baseline (6411.879 us; speedup 1.0000x reference)
//
#include <hip/hip_runtime.h>
#include <math.h>

// ---------------- problem constants (fixed by setup_inputs) ----------------
#define N_    256
#define T_    36
#define M_    50
#define P_    80
#define K_    161          // 1 + 2P
#define PADK  192          // K padded to 16*12, pad cols are zero
#define KC    12           // k-elements per lane (16 lanes per column)
#define NB    200          // blocks (<= 256 CUs, all co-resident)
#define NT    512          // threads/block; 8 waves -> 2 per SIMD
                           // 200*512/16*2 = 12800 columns
#define LAM_  0.1f
#define MAXIT 100

#define KM_     (K_*M_)        // 8050
#define TM_     (T_*M_)        // 1800
#define OUT_DIC 2060800        // N*K*M
#define OUT_REC 2066596        // + T*K

// ---- workspace float offsets ----
#define WS_LINV 0
#define WS_D    64             // 36*192 = 6912 floats
#define WS_ACC  8192           // 200 floats (per-iter global sum of dx^2)
#define WS_WN   8392           // 1 float  (sum of wn^2)
#define WS_BARC 8396           // unsigned: barrier count
#define WS_BARG 8397           // unsigned: barrier generation

// ---------------------------------------------------------------------------
// kernel 1: build dictionary (write dic output + padded D to ws) and
// Linv = 1/frob(DtD) using frob(DtD) == frob(D D^T)  (36x36 instead of 161^2)
// ---------------------------------------------------------------------------
__global__ __launch_bounds__(256) void k_dict(const float* __restrict__ rr,
                                              const float* __restrict__ th,
                                              float* __restrict__ out,
                                              float* __restrict__ ws) {
    __shared__ float Dl[T_*PADK];
    const int tid = threadIdx.x;
    for (int e = tid; e < T_*PADK; e += 256) {
        int t = e / PADK, k = e - (e / PADK) * PADK;
        float v = 0.f;
        if (k == 0) v = 1.f;
        else if (k <= P_)      { float r = rr[k-1];     float a = th[k-1]*(float)t;
                                 v = powf(r, (float)t) * cosf(a); }
        else if (k <= 2*P_)    { float r = rr[k-1-P_];  float a = th[k-1-P_]*(float)t;
                                 v = powf(r, (float)t) * sinf(a); }
        Dl[e] = v;
        ws[WS_D + e] = v;
        if (k < K_) out[OUT_DIC + t*K_ + k] = v;
    }
    __syncthreads();
    float loc = 0.f;
    for (int e = tid; e < T_*T_; e += 256) {
        int t1 = e / T_, t2 = e - (e / T_) * T_;
        float s = 0.f;
        for (int k = 0; k < K_; ++k) s = fmaf(Dl[t1*PADK+k], Dl[t2*PADK+k], s);
        loc = fmaf(s, s, loc);
    }
    #pragma unroll
    for (int mm = 1; mm < 64; mm <<= 1) loc += __shfl_xor(loc, mm);
    __shared__ float rb[4];
    if ((tid & 63) == 0) rb[tid >> 6] = loc;
    __syncthreads();
    if (tid == 0) {
        float tot = rb[0] + rb[1] + rb[2] + rb[3];
        ws[WS_LINV] = 1.0f / sqrtf(tot);
    }
}

// ---------------------------------------------------------------------------
// handmade grid barrier (generation-based; all NB blocks are co-resident)
// ---------------------------------------------------------------------------
__device__ __forceinline__ void grid_barrier(unsigned* cnt, unsigned* gen) {
    __syncthreads();
    if (threadIdx.x == 0) {
        __threadfence();
        unsigned g0 = __hip_atomic_load(gen, __ATOMIC_ACQUIRE, __HIP_MEMORY_SCOPE_AGENT);
        unsigned my = __hip_atomic_fetch_add(cnt, 1u, __ATOMIC_ACQ_REL, __HIP_MEMORY_SCOPE_AGENT);
        if (my == NB - 1u) {
            __hip_atomic_store(cnt, 0u, __ATOMIC_RELAXED, __HIP_MEMORY_SCOPE_AGENT);
            __hip_atomic_fetch_add(gen, 1u, __ATOMIC_RELEASE, __HIP_MEMORY_SCOPE_AGENT);
        } else {
            while (__hip_atomic_load(gen, __ATOMIC_ACQUIRE, __HIP_MEMORY_SCOPE_AGENT) == g0)
                __builtin_amdgcn_s_sleep(1);
        }
        __threadfence();
    }
    __syncthreads();
}

// ---- DPP-based 16-lane sum (pure VALU, off the LDS pipe) -------------------
// Butterfly with mirrors: after xor1+xor2 each quad is uniform, so
// row_half_mirror fetches the other quad's sum; after that each 8-group is
// uniform, so row_mirror fetches the other 8-group within the 16-row.
// All 16 lanes end with the identical fp32 value.
template<int CTRL>
__device__ __forceinline__ float dpp_mov(float v) {
    int p = __builtin_amdgcn_update_dpp(0, __float_as_int(v), CTRL, 0xF, 0xF, true);
    return __int_as_float(p);
}
__device__ __forceinline__ float reduce16(float z) {
    z += dpp_mov<0xB1>(z);     // quad_perm [1,0,3,2]  (xor 1)
    z += dpp_mov<0x4E>(z);     // quad_perm [2,3,0,1]  (xor 2)
    z += dpp_mov<0x141>(z);    // row_half_mirror      (other quad)
    z += dpp_mov<0x140>(z);    // row_mirror           (other 8-group)
    return z;
}

// ---------------------------------------------------------------------------
// kernel 2: persistent FISTA. Each column (n,m) is split across 16 lanes
// (sub = lane&15, 12 k's each, zero-padded). 2 columns per thread amortize
// LDS D-tile reads. State fully in registers; waves_per_eu(2,2) pins the
// allocator to the 256-reg / 2-waves-per-SIMD operating point (no spill,
// no occupancy-chasing 128-reg target).
// ---------------------------------------------------------------------------
__global__ __attribute__((amdgpu_flat_work_group_size(NT, NT),
                          amdgpu_waves_per_eu(2, 2)))
void k_fista(const float* __restrict__ X,
             float* __restrict__ out,
             float* __restrict__ ws) {
    __shared__ __align__(16) float Dl[T_*PADK];
    __shared__ int   sniter;
    __shared__ float sbcast;

    unsigned* wsu = (unsigned*)ws;
    const int tid = threadIdx.x;

    for (int e = tid; e < T_*PADK; e += NT) Dl[e] = ws[WS_D + e];
    const float Linv = ws[WS_LINV];
    __syncthreads();

    const int lane  = tid & 63;
    const int sub   = lane & 15;
    const int gw    = (int)blockIdx.x * (NT/64) + (tid >> 6);
    const int colb  = gw*8 + (lane >> 4)*2;        // [0, 12800), 2 cols/thread
    const int n0    = colb / M_;
    const int m0    = colb - n0*M_;
    const int n1    = (colb+1) / M_;
    const int m1    = (colb+1) - n1*M_;
    const int kbase = sub * KC;                    // sub>=14 -> pad region
    const float* Y0 = X + n0*TM_ + m0;
    const float* Y1 = X + n1*TM_ + m1;

    const float4* __restrict__ Drow = (const float4*)(Dl + kbase);
    // row stride in float4s
    #define DSTRIDE (PADK/4)

    float x[2][KC], y[2][KC], b[2][KC], wl[2][KC];

    // ---- b = Linv * (D^T Ycol) for both columns ----
    #pragma unroll
    for (int j = 0; j < KC; ++j) { b[0][j] = 0.f; b[1][j] = 0.f; }
    #pragma unroll 2
    for (int t = 0; t < T_; ++t) {
        float yv0 = Y0[t*M_], yv1 = Y1[t*M_];
        #pragma unroll
        for (int q = 0; q < KC/4; ++q) {
            float4 d = Drow[t*DSTRIDE + q];
            b[0][4*q+0] = fmaf(d.x, yv0, b[0][4*q+0]);
            b[0][4*q+1] = fmaf(d.y, yv0, b[0][4*q+1]);
            b[0][4*q+2] = fmaf(d.z, yv0, b[0][4*q+2]);
            b[0][4*q+3] = fmaf(d.w, yv0, b[0][4*q+3]);
            b[1][4*q+0] = fmaf(d.x, yv1, b[1][4*q+0]);
            b[1][4*q+1] = fmaf(d.y, yv1, b[1][4*q+1]);
            b[1][4*q+2] = fmaf(d.z, yv1, b[1][4*q+2]);
            b[1][4*q+3] = fmaf(d.w, yv1, b[1][4*q+3]);
        }
    }
    #pragma unroll
    for (int j = 0; j < KC; ++j) { b[0][j] *= Linv; b[1][j] *= Linv; }

    // pass-1 weights: w = 1 -> wl = lam*Linv
    #pragma unroll
    for (int j = 0; j < KC; ++j) { wl[0][j] = LAM_ * Linv; wl[1][j] = LAM_ * Linv; }

    float tcur = 1.f;

    // one FISTA iteration for both columns; returns this thread's sum of dx^2
    auto iterate = [&]() -> float {
        float u[2][KC];
        #pragma unroll
        for (int j = 0; j < KC; ++j) { u[0][j] = 0.f; u[1][j] = 0.f; }

        // per-t body given this thread's D slice (3 float4s)
        auto tbody = [&](float4 d0, float4 d1, float4 d2) {
            float4 da[3] = {d0, d1, d2};
            float z00=0.f, z01=0.f, z02=0.f, z03=0.f;
            float z10=0.f, z11=0.f, z12=0.f, z13=0.f;
            #pragma unroll
            for (int q = 0; q < 3; ++q) {
                z00 = fmaf(da[q].x, y[0][4*q+0], z00);
                z01 = fmaf(da[q].y, y[0][4*q+1], z01);
                z02 = fmaf(da[q].z, y[0][4*q+2], z02);
                z03 = fmaf(da[q].w, y[0][4*q+3], z03);
                z10 = fmaf(da[q].x, y[1][4*q+0], z10);
                z11 = fmaf(da[q].y, y[1][4*q+1], z11);
                z12 = fmaf(da[q].z, y[1][4*q+2], z12);
                z13 = fmaf(da[q].w, y[1][4*q+3], z13);
            }
            float z0 = (z00+z01) + (z02+z03);
            float z1 = (z10+z11) + (z12+z13);
            z0 = reduce16(z0);                     // all 16 lanes hold z_t
            z1 = reduce16(z1);
            #pragma unroll
            for (int q = 0; q < 3; ++q) {
                u[0][4*q+0] = fmaf(da[q].x, z0, u[0][4*q+0]);
                u[0][4*q+1] = fmaf(da[q].y, z0, u[0][4*q+1]);
                u[0][4*q+2] = fmaf(da[q].z, z0, u[0][4*q+2]);
                u[0][4*q+3] = fmaf(da[q].w, z0, u[0][4*q+3]);
                u[1][4*q+0] = fmaf(da[q].x, z1, u[1][4*q+0]);
                u[1][4*q+1] = fmaf(da[q].y, z1, u[1][4*q+1]);
                u[1][4*q+2] = fmaf(da[q].z, z1, u[1][4*q+2]);
                u[1][4*q+3] = fmaf(da[q].w, z1, u[1][4*q+3]);
            }
        };

        // depth-1 software prefetch over t so the ds_read latency hides
        // under the ~56-instr FMA/DPP chain of the previous row
        float4 a0 = Drow[0], a1 = Drow[1], a2 = Drow[2];
        #pragma unroll 3
        for (int t = 0; t < T_ - 1; ++t) {
            float4 p0 = Drow[(t+1)*DSTRIDE + 0];
            float4 p1 = Drow[(t+1)*DSTRIDE + 1];
            float4 p2 = Drow[(t+1)*DSTRIDE + 2];
            tbody(a0, a1, a2);
            a0 = p0; a1 = p1; a2 = p2;
        }
        tbody(a0, a1, a2);

        float t0 = tcur;
        float t1 = 0.5f * (1.f + sqrtf(fmaf(4.f*t0, t0, 1.f)));
        float tt = (t0 - 1.f) / t1;
        tcur = t1;
        float ss = 0.f;
        #pragma unroll
        for (int c = 0; c < 2; ++c) {
            #pragma unroll
            for (int j = 0; j < KC; ++j) {
                float Ay = fmaf(-Linv, u[c][j], y[c][j]);  // y - Linv*D^T(D y)
                float s  = Ay + b[c][j];
                float xn = fmaxf(0.f, s - wl[c][j]) + fminf(0.f, s + wl[c][j]);
                float d  = xn - x[c][j];
                ss    = fmaf(d, d, ss);
                y[c][j] = fmaf(tt, d, xn);
                x[c][j] = xn;
            }
        }
        return ss;
    };

    auto run = [&](int nit, bool record, int accbase) {
        tcur = 1.f;
        #pragma unroll
        for (int j = 0; j < KC; ++j) {
            x[0][j] = 0.f; x[1][j] = 0.f; y[0][j] = 0.f; y[1][j] = 0.f;
        }
        for (int i = 0; i < nit; ++i) {
            float ss = iterate();
            if (record) {
                #pragma unroll
                for (int mm = 1; mm < 64; mm <<= 1) ss += __shfl_xor(ss, mm);
                if (lane == 0) atomicAdd(ws + WS_ACC + accbase + i, ss);
            }
        }
    };

    const float THR2 = (1e-5f * (float)K_) * (1e-5f * (float)K_);  // (tol*K)^2

    #pragma unroll 1
    for (int pass = 0; pass < 2; ++pass) {
        // run 1: full 100 iters, record per-iter ||dx||^2 (fire-and-forget)
        run(MAXIT, true, pass*MAXIT);
        grid_barrier(wsu + WS_BARC, wsu + WS_BARG);

        // find c = first iter with conv; needed iters = c+1 (101 = never)
        if (tid == 0) sniter = MAXIT + 1;
        __syncthreads();
        if (tid < MAXIT) {
            float a = __hip_atomic_load(ws + WS_ACC + pass*MAXIT + tid,
                                        __ATOMIC_RELAXED, __HIP_MEMORY_SCOPE_AGENT);
            if (a < THR2) atomicMin(&sniter, tid + 1);
        }
        __syncthreads();
        int nit2 = sniter;                 // uniform across the whole grid
        if (nit2 < MAXIT) run(nit2, false, 0);   // deterministic replay to x_{c+1}

        if (pass == 0) {
            // reweight: wn = 1/(|code|+0.01); w = wn/||wn||*K; wl = w*lam*Linv
            float loc = 0.f;
            #pragma unroll
            for (int c = 0; c < 2; ++c) {
                #pragma unroll
                for (int j = 0; j < KC; ++j) {
                    float wn = 1.0f / (fabsf(x[c][j]) + 0.01f);
                    wl[c][j] = wn;
                    if (kbase + j < K_) loc = fmaf(wn, wn, loc);   // mask pad k
                }
            }
            #pragma unroll
            for (int mm = 1; mm < 64; mm <<= 1) loc += __shfl_xor(loc, mm);
            if (lane == 0) atomicAdd(ws + WS_WN, loc);
            grid_barrier(wsu + WS_BARC, wsu + WS_BARG);
            if (tid == 0)
                sbcast = __hip_atomic_load(ws + WS_WN, __ATOMIC_RELAXED,
                                           __HIP_MEMORY_SCOPE_AGENT);
            __syncthreads();
            float scale = ((float)K_) * (LAM_ * Linv) / sqrtf(sbcast);
            #pragma unroll
            for (int j = 0; j < KC; ++j) { wl[0][j] *= scale; wl[1][j] *= scale; }
        }
    }

    // ---- outputs: code ----
    #pragma unroll
    for (int j = 0; j < KC; ++j) {
        int kg = kbase + j;
        if (kg < K_) {
            out[n0*KM_ + kg*M_ + m0] = x[0][j];
            out[n1*KM_ + kg*M_ + m1] = x[1][j];
        }
    }
    // ---- reconst = D @ code (on final x, both columns) ----
    #pragma unroll 2
    for (int t = 0; t < T_; ++t) {
        float z00=0.f, z01=0.f, z02=0.f, z03=0.f;
        float z10=0.f, z11=0.f, z12=0.f, z13=0.f;
        #pragma unroll
        for (int q = 0; q < KC/4; ++q) {
            float4 d = Drow[t*DSTRIDE + q];
            z00 = fmaf(d.x, x[0][4*q+0], z00);
            z01 = fmaf(d.y, x[0][4*q+1], z01);
            z02 = fmaf(d.z, x[0][4*q+2], z02);
            z03 = fmaf(d.w, x[0][4*q+3], z03);
            z10 = fmaf(d.x, x[1][4*q+0], z10);
            z11 = fmaf(d.y, x[1][4*q+1], z11);
            z12 = fmaf(d.z, x[1][4*q+2], z12);
            z13 = fmaf(d.w, x[1][4*q+3], z13);
        }
        float z0 = (z00+z01) + (z02+z03);
        float z1 = (z10+z11) + (z12+z13);
        z0 = reduce16(z0);
        z1 = reduce16(z1);
        if (sub == (t & 15)) {
            out[OUT_REC + n0*TM_ + t*M_ + m0] = z0;
            out[OUT_REC + n1*TM_ + t*M_ + m1] = z1;
        }
    }
}

// ---------------------------------------------------------------------------
extern "C" void kernel_launch(void* const* d_in, const int* in_sizes, int n_in,
                              void* d_out, int out_size, void* d_ws, size_t ws_size,
                              hipStream_t stream) {
    const float* X  = (const float*)d_in[0];
    const float* rr = (const float*)d_in[1];
    const float* th = (const float*)d_in[2];
    float* out = (float*)d_out;
    float* ws  = (float*)d_ws;

    // zero conv accumulators + wn accumulator + barrier state (every call)
    hipMemsetAsync((char*)d_ws + WS_ACC*sizeof(float), 0, 4096, stream);
    k_dict<<<dim3(1), dim3(256), 0, stream>>>(rr, th, out, ws);
    k_fista<<<dim3(NB), dim3(NT), 0, stream>>>(X, out, ws);
}

// Round 5
// 2589.520 us; speedup vs baseline: 2.4761x; 2.4761x over previous
//
#include <hip/hip_runtime.h>
#include <math.h>

// ---------------- problem constants (fixed by setup_inputs) ----------------
#define N_    256
#define T_    36
#define M_    50
#define P_    80
#define K_    161          // 1 + 2P
#define PADK  192          // K padded to 16*12, pad cols are zero
#define KC    12           // k-elements per lane (16 lanes per column)
#define NBR   400          // run-kernel blocks: 400*4 waves = 1600 waves
#define NTR   256          // 4 waves/block -> allocator-friendly (no spill, r2)
#define LAM_  0.1f
#define MAXIT 100

#define KM_     (K_*M_)        // 8050
#define TM_     (T_*M_)        // 1800
#define OUT_DIC 2060800        // N*K*M
#define OUT_REC 2066596        // + T*K

// ---- workspace float offsets ----
#define WS_LINV 0
#define WS_D    64             // 36*192 = 6912 floats
#define WS_ACC  8192           // 200 floats (per-iter global sum of dx^2)
#define WS_WN   8392           // 1 float  (sum of wn^2 over pass-1 code)
#define WS_NIT1 8394           // int slot: pass-1 replay count (101 = none)
#define WS_NIT2 8395           // int slot: pass-2 replay count

// ---------------------------------------------------------------------------
// kernel 1: build dictionary (write dic output + padded D to ws) and
// Linv = 1/frob(DtD) using frob(DtD) == frob(D D^T)  (36x36 instead of 161^2)
// ---------------------------------------------------------------------------
__global__ __launch_bounds__(256) void k_dict(const float* __restrict__ rr,
                                              const float* __restrict__ th,
                                              float* __restrict__ out,
                                              float* __restrict__ ws) {
    __shared__ float Dl[T_*PADK];
    const int tid = threadIdx.x;
    for (int e = tid; e < T_*PADK; e += 256) {
        int t = e / PADK, k = e - (e / PADK) * PADK;
        float v = 0.f;
        if (k == 0) v = 1.f;
        else if (k <= P_)      { float r = rr[k-1];     float a = th[k-1]*(float)t;
                                 v = powf(r, (float)t) * cosf(a); }
        else if (k <= 2*P_)    { float r = rr[k-1-P_];  float a = th[k-1-P_]*(float)t;
                                 v = powf(r, (float)t) * sinf(a); }
        Dl[e] = v;
        ws[WS_D + e] = v;
        if (k < K_) out[OUT_DIC + t*K_ + k] = v;
    }
    __syncthreads();
    float loc = 0.f;
    for (int e = tid; e < T_*T_; e += 256) {
        int t1 = e / T_, t2 = e - (e / T_) * T_;
        float s = 0.f;
        for (int k = 0; k < K_; ++k) s = fmaf(Dl[t1*PADK+k], Dl[t2*PADK+k], s);
        loc = fmaf(s, s, loc);
    }
    #pragma unroll
    for (int mm = 1; mm < 64; mm <<= 1) loc += __shfl_xor(loc, mm);
    __shared__ float rb[4];
    if ((tid & 63) == 0) rb[tid >> 6] = loc;
    __syncthreads();
    if (tid == 0) {
        float tot = rb[0] + rb[1] + rb[2] + rb[3];
        ws[WS_LINV] = 1.0f / sqrtf(tot);
    }
}

// ---- DPP-based 16-lane sum (pure VALU, off the LDS pipe) -------------------
template<int CTRL>
__device__ __forceinline__ float dpp_mov(float v) {
    int p = __builtin_amdgcn_update_dpp(0, __float_as_int(v), CTRL, 0xF, 0xF, true);
    return __int_as_float(p);
}
__device__ __forceinline__ float reduce16(float z) {
    z += dpp_mov<0xB1>(z);     // quad_perm [1,0,3,2]  (xor 1)
    z += dpp_mov<0x4E>(z);     // quad_perm [2,3,0,1]  (xor 2)
    z += dpp_mov<0x141>(z);    // row_half_mirror      (other quad)
    z += dpp_mov<0x140>(z);    // row_mirror           (other 8-group)
    return z;
}

// ---------------------------------------------------------------------------
// shared device pieces (all arrays indexed by fully-unrolled loops -> regs)
// ---------------------------------------------------------------------------
__device__ __forceinline__ void compute_b(const float* Dl, int kbase, float Linv,
                                          const float* Y0, const float* Y1,
                                          float (&b)[2][KC]) {
    #pragma unroll
    for (int j = 0; j < KC; ++j) { b[0][j] = 0.f; b[1][j] = 0.f; }
    #pragma unroll 2
    for (int t = 0; t < T_; ++t) {
        float yv0 = Y0[t*M_], yv1 = Y1[t*M_];
        const float4* dp = (const float4*)(Dl + t*PADK + kbase);
        float4 da[3] = {dp[0], dp[1], dp[2]};
        #pragma unroll
        for (int q = 0; q < 3; ++q) {
            b[0][4*q+0] = fmaf(da[q].x, yv0, b[0][4*q+0]);
            b[0][4*q+1] = fmaf(da[q].y, yv0, b[0][4*q+1]);
            b[0][4*q+2] = fmaf(da[q].z, yv0, b[0][4*q+2]);
            b[0][4*q+3] = fmaf(da[q].w, yv0, b[0][4*q+3]);
            b[1][4*q+0] = fmaf(da[q].x, yv1, b[1][4*q+0]);
            b[1][4*q+1] = fmaf(da[q].y, yv1, b[1][4*q+1]);
            b[1][4*q+2] = fmaf(da[q].z, yv1, b[1][4*q+2]);
            b[1][4*q+3] = fmaf(da[q].w, yv1, b[1][4*q+3]);
        }
    }
    #pragma unroll
    for (int j = 0; j < KC; ++j) { b[0][j] *= Linv; b[1][j] *= Linv; }
}

// one FISTA iteration (both columns); returns this thread's sum of dx^2
__device__ __forceinline__ float fista_iter(const float* Dl, int kbase, float Linv,
                                            float tt,
                                            float (&x)[2][KC], float (&y)[2][KC],
                                            const float (&b)[2][KC],
                                            const float (&wl)[2][KC]) {
    float u[2][KC];
    #pragma unroll
    for (int j = 0; j < KC; ++j) { u[0][j] = 0.f; u[1][j] = 0.f; }
    #pragma unroll 2
    for (int t = 0; t < T_; ++t) {
        const float4* dp = (const float4*)(Dl + t*PADK + kbase);
        float4 da[3] = {dp[0], dp[1], dp[2]};
        float z00=0.f, z01=0.f, z02=0.f, z03=0.f;
        float z10=0.f, z11=0.f, z12=0.f, z13=0.f;
        #pragma unroll
        for (int q = 0; q < 3; ++q) {
            z00 = fmaf(da[q].x, y[0][4*q+0], z00);
            z01 = fmaf(da[q].y, y[0][4*q+1], z01);
            z02 = fmaf(da[q].z, y[0][4*q+2], z02);
            z03 = fmaf(da[q].w, y[0][4*q+3], z03);
            z10 = fmaf(da[q].x, y[1][4*q+0], z10);
            z11 = fmaf(da[q].y, y[1][4*q+1], z11);
            z12 = fmaf(da[q].z, y[1][4*q+2], z12);
            z13 = fmaf(da[q].w, y[1][4*q+3], z13);
        }
        float z0 = reduce16((z00+z01) + (z02+z03));  // all 16 lanes hold z_t
        float z1 = reduce16((z10+z11) + (z12+z13));
        #pragma unroll
        for (int q = 0; q < 3; ++q) {
            u[0][4*q+0] = fmaf(da[q].x, z0, u[0][4*q+0]);
            u[0][4*q+1] = fmaf(da[q].y, z0, u[0][4*q+1]);
            u[0][4*q+2] = fmaf(da[q].z, z0, u[0][4*q+2]);
            u[0][4*q+3] = fmaf(da[q].w, z0, u[0][4*q+3]);
            u[1][4*q+0] = fmaf(da[q].x, z1, u[1][4*q+0]);
            u[1][4*q+1] = fmaf(da[q].y, z1, u[1][4*q+1]);
            u[1][4*q+2] = fmaf(da[q].z, z1, u[1][4*q+2]);
            u[1][4*q+3] = fmaf(da[q].w, z1, u[1][4*q+3]);
        }
    }
    float ss = 0.f;
    #pragma unroll
    for (int c = 0; c < 2; ++c) {
        #pragma unroll
        for (int j = 0; j < KC; ++j) {
            float Ay = fmaf(-Linv, u[c][j], y[c][j]);   // y - Linv*D^T(D y)
            float s  = Ay + b[c][j];
            float xn = fmaxf(0.f, s - wl[c][j]) + fminf(0.f, s + wl[c][j]);
            float d  = xn - x[c][j];
            ss    = fmaf(d, d, ss);
            y[c][j] = fmaf(tt, d, xn);
            x[c][j] = xn;
        }
    }
    return ss;
}

// run nit iterations from x=y=0; optionally record global ||dx||^2 per iter
__device__ __forceinline__ void run_fista(const float* Dl, int kbase, float Linv,
                                          const float (&b)[2][KC],
                                          const float (&wl)[2][KC],
                                          float (&x)[2][KC], float (&y)[2][KC],
                                          int nit, float* acc, int lane) {
    #pragma unroll
    for (int j = 0; j < KC; ++j) {
        x[0][j] = 0.f; x[1][j] = 0.f; y[0][j] = 0.f; y[1][j] = 0.f;
    }
    float tcur = 1.f;
    for (int i = 0; i < nit; ++i) {
        float tnext = 0.5f * (1.f + sqrtf(fmaf(4.f*tcur, tcur, 1.f)));
        float tt = (tcur - 1.f) / tnext;
        tcur = tnext;
        float ss = fista_iter(Dl, kbase, Linv, tt, x, y, b, wl);
        if (acc) {
            #pragma unroll
            for (int mm = 1; mm < 64; mm <<= 1) ss += __shfl_xor(ss, mm);
            if (lane == 0) atomicAdd(acc + i, ss);
        }
    }
}

// per-thread geometry helper
struct Geo { int n0, m0, n1, m1, kbase, sub, lane; };
__device__ __forceinline__ Geo make_geo() {
    Geo g;
    const int tid = threadIdx.x;
    g.lane = tid & 63;
    g.sub  = g.lane & 15;
    const int gw   = (int)blockIdx.x * (NTR/64) + (tid >> 6);
    const int colb = gw*8 + (g.lane >> 4)*2;       // [0, 12800)
    g.n0 = colb / M_;       g.m0 = colb - g.n0*M_;
    g.n1 = (colb+1) / M_;   g.m1 = (colb+1) - g.n1*M_;
    g.kbase = g.sub * KC;
    return g;
}

__device__ __forceinline__ void load_D_lds(float* Dl, const float* ws) {
    for (int e = threadIdx.x; e < T_*PADK; e += NTR) Dl[e] = ws[WS_D + e];
}

__device__ __forceinline__ void write_code(const Geo& g, const float (&x)[2][KC],
                                           float* out) {
    #pragma unroll
    for (int j = 0; j < KC; ++j) {
        int kg = g.kbase + j;
        if (kg < K_) {
            out[g.n0*KM_ + kg*M_ + g.m0] = x[0][j];
            out[g.n1*KM_ + kg*M_ + g.m1] = x[1][j];
        }
    }
}

__device__ __forceinline__ void load_code(const Geo& g, float (&x)[2][KC],
                                          const float* out) {
    #pragma unroll
    for (int j = 0; j < KC; ++j) {
        int kg = g.kbase + j;
        x[0][j] = (kg < K_) ? out[g.n0*KM_ + kg*M_ + g.m0] : 0.f;
        x[1][j] = (kg < K_) ? out[g.n1*KM_ + kg*M_ + g.m1] : 0.f;
    }
}

__device__ __forceinline__ void write_reconst(const float* Dl, const Geo& g,
                                              const float (&x)[2][KC], float* out) {
    #pragma unroll 2
    for (int t = 0; t < T_; ++t) {
        const float4* dp = (const float4*)(Dl + t*PADK + g.kbase);
        float4 da[3] = {dp[0], dp[1], dp[2]};
        float z00=0.f, z01=0.f, z02=0.f, z03=0.f;
        float z10=0.f, z11=0.f, z12=0.f, z13=0.f;
        #pragma unroll
        for (int q = 0; q < 3; ++q) {
            z00 = fmaf(da[q].x, x[0][4*q+0], z00);
            z01 = fmaf(da[q].y, x[0][4*q+1], z01);
            z02 = fmaf(da[q].z, x[0][4*q+2], z02);
            z03 = fmaf(da[q].w, x[0][4*q+3], z03);
            z10 = fmaf(da[q].x, x[1][4*q+0], z10);
            z11 = fmaf(da[q].y, x[1][4*q+1], z11);
            z12 = fmaf(da[q].z, x[1][4*q+2], z12);
            z13 = fmaf(da[q].w, x[1][4*q+3], z13);
        }
        float z0 = reduce16((z00+z01) + (z02+z03));
        float z1 = reduce16((z10+z11) + (z12+z13));
        if (g.sub == (t & 15)) {
            out[OUT_REC + g.n0*TM_ + t*M_ + g.m0] = z0;
            out[OUT_REC + g.n1*TM_ + t*M_ + g.m1] = z1;
        }
    }
}

// ---------------------------------------------------------------------------
// k_run: one reweighting pass, MAXIT iters, record conv norms, write code.
// pass=0: wl = lam*Linv. pass=1: wl from pass-1 code (in out) + WS_WN.
// ---------------------------------------------------------------------------
__global__ __launch_bounds__(NTR, 1) void k_run(const float* __restrict__ X,
                                                float* __restrict__ out,
                                                float* __restrict__ ws,
                                                int pass) {
    __shared__ __align__(16) float Dl[T_*PADK];
    load_D_lds(Dl, ws);
    const float Linv = ws[WS_LINV];
    __syncthreads();

    Geo g = make_geo();
    float x[2][KC], y[2][KC], b[2][KC], wl[2][KC];
    compute_b(Dl, g.kbase, Linv, X + g.n0*TM_ + g.m0, X + g.n1*TM_ + g.m1, b);

    if (pass == 0) {
        #pragma unroll
        for (int j = 0; j < KC; ++j) { wl[0][j] = LAM_*Linv; wl[1][j] = LAM_*Linv; }
    } else {
        float scale = ((float)K_) * (LAM_ * Linv) / sqrtf(ws[WS_WN]);
        float x1[2][KC];
        load_code(g, x1, out);
        #pragma unroll
        for (int c = 0; c < 2; ++c)
            #pragma unroll
            for (int j = 0; j < KC; ++j)
                wl[c][j] = scale / (fabsf(x1[c][j]) + 0.01f);
    }

    run_fista(Dl, g.kbase, Linv, b, wl, x, y, MAXIT,
              ws + WS_ACC + pass*MAXIT, g.lane);
    write_code(g, x, out);
}

// ---------------------------------------------------------------------------
// k_scan: 1 wave; find first iter with global ||dx||^2 < (tol*K)^2
// ---------------------------------------------------------------------------
__global__ void k_scan(float* __restrict__ ws, int pass) {
    const float THR2 = (1e-5f * (float)K_) * (1e-5f * (float)K_);
    int lane = threadIdx.x;
    int best = MAXIT + 1;
    for (int i = lane; i < MAXIT; i += 64) {
        if (ws[WS_ACC + pass*MAXIT + i] < THR2) best = min(best, i + 1);
    }
    #pragma unroll
    for (int mm = 1; mm < 64; mm <<= 1) best = min(best, __shfl_xor(best, mm));
    if (lane == 0) ((int*)ws)[pass == 0 ? WS_NIT1 : WS_NIT2] = best;
}

// ---------------------------------------------------------------------------
// k_fin1: if pass-1 converged early, replay niter1 iters and rewrite code;
// then accumulate ||wn||^2 into WS_WN. (Expected: no replay -> cheap.)
// ---------------------------------------------------------------------------
__global__ __launch_bounds__(NTR, 1) void k_fin1(const float* __restrict__ X,
                                                 float* __restrict__ out,
                                                 float* __restrict__ ws) {
    __shared__ __align__(16) float Dl[T_*PADK];
    load_D_lds(Dl, ws);
    const float Linv = ws[WS_LINV];
    __syncthreads();

    Geo g = make_geo();
    const int nit1 = ((const int*)ws)[WS_NIT1];
    float x[2][KC];

    if (nit1 <= MAXIT) {
        float y[2][KC], b[2][KC], wl[2][KC];
        compute_b(Dl, g.kbase, Linv, X + g.n0*TM_ + g.m0, X + g.n1*TM_ + g.m1, b);
        #pragma unroll
        for (int j = 0; j < KC; ++j) { wl[0][j] = LAM_*Linv; wl[1][j] = LAM_*Linv; }
        run_fista(Dl, g.kbase, Linv, b, wl, x, y, nit1, nullptr, g.lane);
        write_code(g, x, out);
    } else {
        load_code(g, x, out);
    }

    // wn^2 sum over real k (pads excluded)
    float loc = 0.f;
    #pragma unroll
    for (int c = 0; c < 2; ++c)
        #pragma unroll
        for (int j = 0; j < KC; ++j) {
            if (g.kbase + j < K_) {
                float wn = 1.0f / (fabsf(x[c][j]) + 0.01f);
                loc = fmaf(wn, wn, loc);
            }
        }
    #pragma unroll
    for (int mm = 1; mm < 64; mm <<= 1) loc += __shfl_xor(loc, mm);
    if (g.lane == 0) atomicAdd(ws + WS_WN, loc);
}

// ---------------------------------------------------------------------------
// k_fin2: if pass-2 converged early, re-derive pass-1 x (out-code now holds
// x200), recompute wl, replay niter2 iters, rewrite code. Always write
// reconst from the final code. (Expected: no replay -> just reconst.)
// ---------------------------------------------------------------------------
__global__ __launch_bounds__(NTR, 1) void k_fin2(const float* __restrict__ X,
                                                 float* __restrict__ out,
                                                 float* __restrict__ ws) {
    __shared__ __align__(16) float Dl[T_*PADK];
    load_D_lds(Dl, ws);
    const float Linv = ws[WS_LINV];
    __syncthreads();

    Geo g = make_geo();
    const int nit1 = ((const int*)ws)[WS_NIT1];
    const int nit2 = ((const int*)ws)[WS_NIT2];
    float x[2][KC];

    if (nit2 <= MAXIT) {
        float y[2][KC], b[2][KC], wl[2][KC];
        compute_b(Dl, g.kbase, Linv, X + g.n0*TM_ + g.m0, X + g.n1*TM_ + g.m1, b);
        // re-derive pass-1 final x
        #pragma unroll
        for (int j = 0; j < KC; ++j) { wl[0][j] = LAM_*Linv; wl[1][j] = LAM_*Linv; }
        int nrep1 = nit1 <= MAXIT ? nit1 : MAXIT;
        run_fista(Dl, g.kbase, Linv, b, wl, x, y, nrep1, nullptr, g.lane);
        // pass-2 weights from x1 (global norm already in WS_WN)
        float scale = ((float)K_) * (LAM_ * Linv) / sqrtf(ws[WS_WN]);
        #pragma unroll
        for (int c = 0; c < 2; ++c)
            #pragma unroll
            for (int j = 0; j < KC; ++j)
                wl[c][j] = scale / (fabsf(x[c][j]) + 0.01f);
        run_fista(Dl, g.kbase, Linv, b, wl, x, y, nit2, nullptr, g.lane);
        write_code(g, x, out);
    } else {
        load_code(g, x, out);
    }

    write_reconst(Dl, g, x, out);
}

// ---------------------------------------------------------------------------
extern "C" void kernel_launch(void* const* d_in, const int* in_sizes, int n_in,
                              void* d_out, int out_size, void* d_ws, size_t ws_size,
                              hipStream_t stream) {
    const float* X  = (const float*)d_in[0];
    const float* rr = (const float*)d_in[1];
    const float* th = (const float*)d_in[2];
    float* out = (float*)d_out;
    float* ws  = (float*)d_ws;

    // zero conv accumulators + wn accumulator + niter slots (every call)
    hipMemsetAsync((char*)d_ws + WS_ACC*sizeof(float), 0, 4096, stream);
    k_dict<<<dim3(1),   dim3(256), 0, stream>>>(rr, th, out, ws);
    k_run <<<dim3(NBR), dim3(NTR), 0, stream>>>(X, out, ws, 0);
    k_scan<<<dim3(1),   dim3(64),  0, stream>>>(ws, 0);
    k_fin1<<<dim3(NBR), dim3(NTR), 0, stream>>>(X, out, ws);
    k_run <<<dim3(NBR), dim3(NTR), 0, stream>>>(X, out, ws, 1);
    k_scan<<<dim3(1),   dim3(64),  0, stream>>>(ws, 1);
    k_fin2<<<dim3(NBR), dim3(NTR), 0, stream>>>(X, out, ws);
}

// Round 6
// 1850.110 us; speedup vs baseline: 3.4657x; 1.3997x over previous
//
#include <hip/hip_runtime.h>
#include <math.h>

// ---------------- problem constants (fixed by setup_inputs) ----------------
#define N_    256
#define T_    36
#define M_    50
#define P_    80
#define K_    161          // 1 + 2P
#define PADK  192          // K padded to 16*12, pad cols are zero
#define KC    12           // k-elements per lane (16 lanes per column)
#define NBR   800          // run-kernel blocks (2 waves each -> 1600 waves)
#define NTR   128          // 2 waves/block: wave-granular load balance,
                           // small blocks keep the regalloc honest (r5: 84VGPR+spill)
#define LAM_  0.1f
#define MAXIT 100

#define KM_     (K_*M_)        // 8050
#define TM_     (T_*M_)        // 1800
#define OUT_DIC 2060800        // N*K*M
#define OUT_REC 2066596        // + T*K

// ---- workspace float offsets ----
#define WS_LINV 0
#define WS_D    64             // 36*192 = 6912 floats
#define WS_ACC  8192           // 2 passes * 100 iters * 4 slots = 800 floats
#define WS_WN   9000           // 1 float (sum of wn^2 over pass-1 code)
#define WS_NIT1 9002           // int slot: pass-1 replay count (101 = none)
#define WS_NIT2 9003           // int slot: pass-2 replay count

// ---------------------------------------------------------------------------
// kernel 1: build dictionary (write dic output + padded D to ws) and
// Linv = 1/frob(DtD) using frob(DtD) == frob(D D^T)  (36x36 instead of 161^2)
// ---------------------------------------------------------------------------
__global__ __launch_bounds__(256) void k_dict(const float* __restrict__ rr,
                                              const float* __restrict__ th,
                                              float* __restrict__ out,
                                              float* __restrict__ ws) {
    __shared__ float Dl[T_*PADK];
    const int tid = threadIdx.x;
    for (int e = tid; e < T_*PADK; e += 256) {
        int t = e / PADK, k = e - (e / PADK) * PADK;
        float v = 0.f;
        if (k == 0) v = 1.f;
        else if (k <= P_)      { float r = rr[k-1];     float a = th[k-1]*(float)t;
                                 v = powf(r, (float)t) * cosf(a); }
        else if (k <= 2*P_)    { float r = rr[k-1-P_];  float a = th[k-1-P_]*(float)t;
                                 v = powf(r, (float)t) * sinf(a); }
        Dl[e] = v;
        ws[WS_D + e] = v;
        if (k < K_) out[OUT_DIC + t*K_ + k] = v;
    }
    __syncthreads();
    float loc = 0.f;
    for (int e = tid; e < T_*T_; e += 256) {
        int t1 = e / T_, t2 = e - (e / T_) * T_;
        float s = 0.f;
        for (int k = 0; k < K_; ++k) s = fmaf(Dl[t1*PADK+k], Dl[t2*PADK+k], s);
        loc = fmaf(s, s, loc);
    }
    #pragma unroll
    for (int mm = 1; mm < 64; mm <<= 1) loc += __shfl_xor(loc, mm);
    __shared__ float rb[4];
    if ((tid & 63) == 0) rb[tid >> 6] = loc;
    __syncthreads();
    if (tid == 0) {
        float tot = rb[0] + rb[1] + rb[2] + rb[3];
        ws[WS_LINV] = 1.0f / sqrtf(tot);
    }
}

// ---- DPP-based 16-lane sum (pure VALU, off the LDS pipe) -------------------
template<int CTRL>
__device__ __forceinline__ float dpp_mov(float v) {
    int p = __builtin_amdgcn_update_dpp(0, __float_as_int(v), CTRL, 0xF, 0xF, true);
    return __int_as_float(p);
}
__device__ __forceinline__ float reduce16(float z) {
    z += dpp_mov<0xB1>(z);     // quad_perm [1,0,3,2]  (xor 1)
    z += dpp_mov<0x4E>(z);     // quad_perm [2,3,0,1]  (xor 2)
    z += dpp_mov<0x141>(z);    // row_half_mirror      (other quad)
    z += dpp_mov<0x140>(z);    // row_mirror           (other 8-group)
    return z;
}

// ---------------------------------------------------------------------------
// k_run<PASS>: one reweighting pass, MAXIT iters, record conv norms (4-slot
// spread), write code. Monolithic lambda style (round-2 codegen: no spill).
// PASS 0: scalar wl = lam*Linv, state {x,y,b,u}.
// PASS 1: cm/cp = b -/+ wl(x1) precomputed, state {x,y,cm,cp,u}.
// ---------------------------------------------------------------------------
template<int PASS>
__global__ __launch_bounds__(NTR, 1) void k_run(const float* __restrict__ X,
                                                float* __restrict__ out,
                                                float* __restrict__ ws) {
    __shared__ __align__(16) float Dl[T_*PADK];
    const int tid = threadIdx.x;
    for (int e = tid; e < T_*PADK; e += NTR) Dl[e] = ws[WS_D + e];
    const float Linv = ws[WS_LINV];
    __syncthreads();

    const int lane  = tid & 63;
    const int sub   = lane & 15;
    const int gw    = (int)blockIdx.x * (NTR/64) + (tid >> 6);
    const int colb  = gw*8 + (lane >> 4)*2;        // [0, 12800), 2 cols/thread
    const int n0    = colb / M_;
    const int m0    = colb - n0*M_;
    const int n1    = (colb+1) / M_;
    const int m1    = (colb+1) - n1*M_;
    const int kbase = sub * KC;                    // sub>=14 -> pad region
    const float* Y0 = X + n0*TM_ + m0;
    const float* Y1 = X + n1*TM_ + m1;

    float x[2][KC], y[2][KC], cm[2][KC], cp[2][KC];
    // cm/cp usage: PASS==0 -> cm = b (cp unused); PASS==1 -> cm/cp = b -/+ wl
    const float wlc = LAM_ * Linv;

    // ---- b = Linv * (D^T Ycol), stored into cm ----
    #pragma unroll
    for (int j = 0; j < KC; ++j) { cm[0][j] = 0.f; cm[1][j] = 0.f; }
    #pragma unroll 2
    for (int t = 0; t < T_; ++t) {
        float yv0 = Y0[t*M_], yv1 = Y1[t*M_];
        const float4* dp = (const float4*)(Dl + t*PADK + kbase);
        float4 da[3] = {dp[0], dp[1], dp[2]};
        #pragma unroll
        for (int q = 0; q < 3; ++q) {
            cm[0][4*q+0] = fmaf(da[q].x, yv0, cm[0][4*q+0]);
            cm[0][4*q+1] = fmaf(da[q].y, yv0, cm[0][4*q+1]);
            cm[0][4*q+2] = fmaf(da[q].z, yv0, cm[0][4*q+2]);
            cm[0][4*q+3] = fmaf(da[q].w, yv0, cm[0][4*q+3]);
            cm[1][4*q+0] = fmaf(da[q].x, yv1, cm[1][4*q+0]);
            cm[1][4*q+1] = fmaf(da[q].y, yv1, cm[1][4*q+1]);
            cm[1][4*q+2] = fmaf(da[q].z, yv1, cm[1][4*q+2]);
            cm[1][4*q+3] = fmaf(da[q].w, yv1, cm[1][4*q+3]);
        }
    }
    #pragma unroll
    for (int j = 0; j < KC; ++j) { cm[0][j] *= Linv; cm[1][j] *= Linv; }

    if (PASS == 1) {
        // wl = K*lam*Linv/||wn|| * 1/(|x1|+0.01); cm=b-wl, cp=b+wl
        float scale = ((float)K_) * (LAM_ * Linv) / sqrtf(ws[WS_WN]);
        #pragma unroll
        for (int c = 0; c < 2; ++c) {
            const int nn = c ? n1 : n0, mm2 = c ? m1 : m0;
            #pragma unroll
            for (int j = 0; j < KC; ++j) {
                int kg = kbase + j;
                float x1 = (kg < K_) ? out[nn*KM_ + kg*M_ + mm2] : 0.f;
                float wl = scale / (fabsf(x1) + 0.01f);
                float bb = cm[c][j];
                cm[c][j] = bb - wl;
                cp[c][j] = bb + wl;
            }
        }
    }

    float tcur = 1.f;

    auto iterate = [&](float tt) -> float {
        float u[2][KC];
        #pragma unroll
        for (int j = 0; j < KC; ++j) { u[0][j] = 0.f; u[1][j] = 0.f; }
        #pragma unroll 2
        for (int t = 0; t < T_; ++t) {
            const float4* dp = (const float4*)(Dl + t*PADK + kbase);
            float4 da[3] = {dp[0], dp[1], dp[2]};
            float z00=0.f, z01=0.f, z02=0.f, z03=0.f;
            float z10=0.f, z11=0.f, z12=0.f, z13=0.f;
            #pragma unroll
            for (int q = 0; q < 3; ++q) {
                z00 = fmaf(da[q].x, y[0][4*q+0], z00);
                z01 = fmaf(da[q].y, y[0][4*q+1], z01);
                z02 = fmaf(da[q].z, y[0][4*q+2], z02);
                z03 = fmaf(da[q].w, y[0][4*q+3], z03);
                z10 = fmaf(da[q].x, y[1][4*q+0], z10);
                z11 = fmaf(da[q].y, y[1][4*q+1], z11);
                z12 = fmaf(da[q].z, y[1][4*q+2], z12);
                z13 = fmaf(da[q].w, y[1][4*q+3], z13);
            }
            float z0 = reduce16((z00+z01) + (z02+z03));   // 16 lanes hold z_t
            float z1 = reduce16((z10+z11) + (z12+z13));
            #pragma unroll
            for (int q = 0; q < 3; ++q) {
                u[0][4*q+0] = fmaf(da[q].x, z0, u[0][4*q+0]);
                u[0][4*q+1] = fmaf(da[q].y, z0, u[0][4*q+1]);
                u[0][4*q+2] = fmaf(da[q].z, z0, u[0][4*q+2]);
                u[0][4*q+3] = fmaf(da[q].w, z0, u[0][4*q+3]);
                u[1][4*q+0] = fmaf(da[q].x, z1, u[1][4*q+0]);
                u[1][4*q+1] = fmaf(da[q].y, z1, u[1][4*q+1]);
                u[1][4*q+2] = fmaf(da[q].z, z1, u[1][4*q+2]);
                u[1][4*q+3] = fmaf(da[q].w, z1, u[1][4*q+3]);
            }
        }
        float ss = 0.f;
        #pragma unroll
        for (int c = 0; c < 2; ++c) {
            #pragma unroll
            for (int j = 0; j < KC; ++j) {
                float v = fmaf(-Linv, u[c][j], y[c][j]);   // Ay
                float xn;
                if (PASS == 0) {
                    float s = v + cm[c][j];                 // Ay + b
                    xn = fmaxf(0.f, s - wlc) + fminf(0.f, s + wlc);
                } else {
                    xn = fmaxf(0.f, v + cm[c][j]) + fminf(0.f, v + cp[c][j]);
                }
                float d = xn - x[c][j];
                ss      = fmaf(d, d, ss);
                y[c][j] = fmaf(tt, d, xn);
                x[c][j] = xn;
            }
        }
        return ss;
    };

    #pragma unroll
    for (int j = 0; j < KC; ++j) {
        x[0][j] = 0.f; x[1][j] = 0.f; y[0][j] = 0.f; y[1][j] = 0.f;
    }
    float* acc = ws + WS_ACC + PASS*4*MAXIT;
    for (int i = 0; i < MAXIT; ++i) {
        float tnext = 0.5f * (1.f + sqrtf(fmaf(4.f*tcur, tcur, 1.f)));
        float tt = (tcur - 1.f) / tnext;
        tcur = tnext;
        float ss = iterate(tt);
        #pragma unroll
        for (int mm = 1; mm < 64; mm <<= 1) ss += __shfl_xor(ss, mm);
        if (lane == 0) atomicAdd(acc + i*4 + (gw & 3), ss);   // fire-and-forget
    }

    // ---- write code ----
    #pragma unroll
    for (int j = 0; j < KC; ++j) {
        int kg = kbase + j;
        if (kg < K_) {
            out[n0*KM_ + kg*M_ + m0] = x[0][j];
            out[n1*KM_ + kg*M_ + m1] = x[1][j];
        }
    }
}

// ---------------------------------------------------------------------------
// helpers for the (rarely-executed) replay/finish kernels
// ---------------------------------------------------------------------------
struct Geo { int n0, m0, n1, m1, kbase, sub, lane; };
__device__ __forceinline__ Geo make_geo() {
    Geo g;
    const int tid = threadIdx.x;
    g.lane = tid & 63;
    g.sub  = g.lane & 15;
    const int gw   = (int)blockIdx.x * (NTR/64) + (tid >> 6);
    const int colb = gw*8 + (g.lane >> 4)*2;
    g.n0 = colb / M_;       g.m0 = colb - g.n0*M_;
    g.n1 = (colb+1) / M_;   g.m1 = (colb+1) - g.n1*M_;
    g.kbase = g.sub * KC;
    return g;
}

__device__ __forceinline__ void compute_b(const float* Dl, int kbase, float Linv,
                                          const float* Y0, const float* Y1,
                                          float (&b)[2][KC]) {
    #pragma unroll
    for (int j = 0; j < KC; ++j) { b[0][j] = 0.f; b[1][j] = 0.f; }
    #pragma unroll 2
    for (int t = 0; t < T_; ++t) {
        float yv0 = Y0[t*M_], yv1 = Y1[t*M_];
        const float4* dp = (const float4*)(Dl + t*PADK + kbase);
        float4 da[3] = {dp[0], dp[1], dp[2]};
        #pragma unroll
        for (int q = 0; q < 3; ++q) {
            b[0][4*q+0] = fmaf(da[q].x, yv0, b[0][4*q+0]);
            b[0][4*q+1] = fmaf(da[q].y, yv0, b[0][4*q+1]);
            b[0][4*q+2] = fmaf(da[q].z, yv0, b[0][4*q+2]);
            b[0][4*q+3] = fmaf(da[q].w, yv0, b[0][4*q+3]);
            b[1][4*q+0] = fmaf(da[q].x, yv1, b[1][4*q+0]);
            b[1][4*q+1] = fmaf(da[q].y, yv1, b[1][4*q+1]);
            b[1][4*q+2] = fmaf(da[q].z, yv1, b[1][4*q+2]);
            b[1][4*q+3] = fmaf(da[q].w, yv1, b[1][4*q+3]);
        }
    }
    #pragma unroll
    for (int j = 0; j < KC; ++j) { b[0][j] *= Linv; b[1][j] *= Linv; }
}

// generic FISTA run with per-element cm/cp (used only on replay paths)
__device__ __forceinline__ void run_fista(const float* Dl, int kbase, float Linv,
                                          const float (&cmv)[2][KC],
                                          const float (&cpv)[2][KC],
                                          float (&x)[2][KC], int nit) {
    float y[2][KC];
    #pragma unroll
    for (int j = 0; j < KC; ++j) {
        x[0][j] = 0.f; x[1][j] = 0.f; y[0][j] = 0.f; y[1][j] = 0.f;
    }
    float tcur = 1.f;
    for (int i = 0; i < nit; ++i) {
        float tnext = 0.5f * (1.f + sqrtf(fmaf(4.f*tcur, tcur, 1.f)));
        float tt = (tcur - 1.f) / tnext;
        tcur = tnext;
        float u[2][KC];
        #pragma unroll
        for (int j = 0; j < KC; ++j) { u[0][j] = 0.f; u[1][j] = 0.f; }
        #pragma unroll 2
        for (int t = 0; t < T_; ++t) {
            const float4* dp = (const float4*)(Dl + t*PADK + kbase);
            float4 da[3] = {dp[0], dp[1], dp[2]};
            float z00=0.f, z01=0.f, z02=0.f, z03=0.f;
            float z10=0.f, z11=0.f, z12=0.f, z13=0.f;
            #pragma unroll
            for (int q = 0; q < 3; ++q) {
                z00 = fmaf(da[q].x, y[0][4*q+0], z00);
                z01 = fmaf(da[q].y, y[0][4*q+1], z01);
                z02 = fmaf(da[q].z, y[0][4*q+2], z02);
                z03 = fmaf(da[q].w, y[0][4*q+3], z03);
                z10 = fmaf(da[q].x, y[1][4*q+0], z10);
                z11 = fmaf(da[q].y, y[1][4*q+1], z11);
                z12 = fmaf(da[q].z, y[1][4*q+2], z12);
                z13 = fmaf(da[q].w, y[1][4*q+3], z13);
            }
            float z0 = reduce16((z00+z01) + (z02+z03));
            float z1 = reduce16((z10+z11) + (z12+z13));
            #pragma unroll
            for (int q = 0; q < 3; ++q) {
                u[0][4*q+0] = fmaf(da[q].x, z0, u[0][4*q+0]);
                u[0][4*q+1] = fmaf(da[q].y, z0, u[0][4*q+1]);
                u[0][4*q+2] = fmaf(da[q].z, z0, u[0][4*q+2]);
                u[0][4*q+3] = fmaf(da[q].w, z0, u[0][4*q+3]);
                u[1][4*q+0] = fmaf(da[q].x, z1, u[1][4*q+0]);
                u[1][4*q+1] = fmaf(da[q].y, z1, u[1][4*q+1]);
                u[1][4*q+2] = fmaf(da[q].z, z1, u[1][4*q+2]);
                u[1][4*q+3] = fmaf(da[q].w, z1, u[1][4*q+3]);
            }
        }
        #pragma unroll
        for (int c = 0; c < 2; ++c) {
            #pragma unroll
            for (int j = 0; j < KC; ++j) {
                float v = fmaf(-Linv, u[c][j], y[c][j]);
                float xn = fmaxf(0.f, v + cmv[c][j]) + fminf(0.f, v + cpv[c][j]);
                float d = xn - x[c][j];
                y[c][j] = fmaf(tt, d, xn);
                x[c][j] = xn;
            }
        }
    }
}

__device__ __forceinline__ void write_code_g(const Geo& g, const float (&x)[2][KC],
                                             float* out) {
    #pragma unroll
    for (int j = 0; j < KC; ++j) {
        int kg = g.kbase + j;
        if (kg < K_) {
            out[g.n0*KM_ + kg*M_ + g.m0] = x[0][j];
            out[g.n1*KM_ + kg*M_ + g.m1] = x[1][j];
        }
    }
}
__device__ __forceinline__ void load_code_g(const Geo& g, float (&x)[2][KC],
                                            const float* out) {
    #pragma unroll
    for (int j = 0; j < KC; ++j) {
        int kg = g.kbase + j;
        x[0][j] = (kg < K_) ? out[g.n0*KM_ + kg*M_ + g.m0] : 0.f;
        x[1][j] = (kg < K_) ? out[g.n1*KM_ + kg*M_ + g.m1] : 0.f;
    }
}

// ---------------------------------------------------------------------------
// k_scan: find first iter with global ||dx||^2 < (tol*K)^2 (4 slots per iter)
// ---------------------------------------------------------------------------
__global__ void k_scan(float* __restrict__ ws, int pass) {
    const float THR2 = (1e-5f * (float)K_) * (1e-5f * (float)K_);
    int lane = threadIdx.x;
    const float* acc = ws + WS_ACC + pass*4*MAXIT;
    int best = MAXIT + 1;
    for (int i = lane; i < MAXIT; i += 64) {
        float a = (acc[i*4] + acc[i*4+1]) + (acc[i*4+2] + acc[i*4+3]);
        if (a < THR2) best = min(best, i + 1);
    }
    #pragma unroll
    for (int mm = 1; mm < 64; mm <<= 1) best = min(best, __shfl_xor(best, mm));
    if (lane == 0) ((int*)ws)[pass == 0 ? WS_NIT1 : WS_NIT2] = best;
}

// ---------------------------------------------------------------------------
// k_fin1: if pass-1 converged early, replay nit1 iters and rewrite code;
// then accumulate ||wn||^2 into WS_WN. (Expected: no replay -> cheap.)
// ---------------------------------------------------------------------------
__global__ __launch_bounds__(NTR, 1) void k_fin1(const float* __restrict__ X,
                                                 float* __restrict__ out,
                                                 float* __restrict__ ws) {
    __shared__ __align__(16) float Dl[T_*PADK];
    for (int e = threadIdx.x; e < T_*PADK; e += NTR) Dl[e] = ws[WS_D + e];
    const float Linv = ws[WS_LINV];
    __syncthreads();

    Geo g = make_geo();
    const int nit1 = ((const int*)ws)[WS_NIT1];
    float x[2][KC];

    if (nit1 <= MAXIT) {
        float b[2][KC], cmv[2][KC], cpv[2][KC];
        compute_b(Dl, g.kbase, Linv, X + g.n0*TM_ + g.m0, X + g.n1*TM_ + g.m1, b);
        const float wlc = LAM_ * Linv;
        #pragma unroll
        for (int c = 0; c < 2; ++c)
            #pragma unroll
            for (int j = 0; j < KC; ++j) { cmv[c][j] = b[c][j] - wlc;
                                           cpv[c][j] = b[c][j] + wlc; }
        run_fista(Dl, g.kbase, Linv, cmv, cpv, x, nit1);
        write_code_g(g, x, out);
    } else {
        load_code_g(g, x, out);
    }

    float loc = 0.f;
    #pragma unroll
    for (int c = 0; c < 2; ++c)
        #pragma unroll
        for (int j = 0; j < KC; ++j) {
            if (g.kbase + j < K_) {
                float wn = 1.0f / (fabsf(x[c][j]) + 0.01f);
                loc = fmaf(wn, wn, loc);
            }
        }
    #pragma unroll
    for (int mm = 1; mm < 64; mm <<= 1) loc += __shfl_xor(loc, mm);
    if (g.lane == 0) atomicAdd(ws + WS_WN, loc);
}

// ---------------------------------------------------------------------------
// k_fin2: if pass-2 converged early, re-derive pass-1 x, recompute weights,
// replay nit2 iters, rewrite code. Always write reconst from final code.
// ---------------------------------------------------------------------------
__global__ __launch_bounds__(NTR, 1) void k_fin2(const float* __restrict__ X,
                                                 float* __restrict__ out,
                                                 float* __restrict__ ws) {
    __shared__ __align__(16) float Dl[T_*PADK];
    for (int e = threadIdx.x; e < T_*PADK; e += NTR) Dl[e] = ws[WS_D + e];
    const float Linv = ws[WS_LINV];
    __syncthreads();

    Geo g = make_geo();
    const int nit1 = ((const int*)ws)[WS_NIT1];
    const int nit2 = ((const int*)ws)[WS_NIT2];
    float x[2][KC];

    if (nit2 <= MAXIT) {
        float b[2][KC], cmv[2][KC], cpv[2][KC];
        compute_b(Dl, g.kbase, Linv, X + g.n0*TM_ + g.m0, X + g.n1*TM_ + g.m1, b);
        const float wlc = LAM_ * Linv;
        #pragma unroll
        for (int c = 0; c < 2; ++c)
            #pragma unroll
            for (int j = 0; j < KC; ++j) { cmv[c][j] = b[c][j] - wlc;
                                           cpv[c][j] = b[c][j] + wlc; }
        int nrep1 = nit1 <= MAXIT ? nit1 : MAXIT;
        run_fista(Dl, g.kbase, Linv, cmv, cpv, x, nrep1);
        float scale = ((float)K_) * (LAM_ * Linv) / sqrtf(ws[WS_WN]);
        #pragma unroll
        for (int c = 0; c < 2; ++c)
            #pragma unroll
            for (int j = 0; j < KC; ++j) {
                float wl = scale / (fabsf(x[c][j]) + 0.01f);
                cmv[c][j] = b[c][j] - wl;
                cpv[c][j] = b[c][j] + wl;
            }
        run_fista(Dl, g.kbase, Linv, cmv, cpv, x, nit2);
        write_code_g(g, x, out);
    } else {
        load_code_g(g, x, out);
    }

    // ---- reconst = D @ code ----
    #pragma unroll 2
    for (int t = 0; t < T_; ++t) {
        const float4* dp = (const float4*)(Dl + t*PADK + g.kbase);
        float4 da[3] = {dp[0], dp[1], dp[2]};
        float z00=0.f, z01=0.f, z02=0.f, z03=0.f;
        float z10=0.f, z11=0.f, z12=0.f, z13=0.f;
        #pragma unroll
        for (int q = 0; q < 3; ++q) {
            z00 = fmaf(da[q].x, x[0][4*q+0], z00);
            z01 = fmaf(da[q].y, x[0][4*q+1], z01);
            z02 = fmaf(da[q].z, x[0][4*q+2], z02);
            z03 = fmaf(da[q].w, x[0][4*q+3], z03);
            z10 = fmaf(da[q].x, x[1][4*q+0], z10);
            z11 = fmaf(da[q].y, x[1][4*q+1], z11);
            z12 = fmaf(da[q].z, x[1][4*q+2], z12);
            z13 = fmaf(da[q].w, x[1][4*q+3], z13);
        }
        float z0 = reduce16((z00+z01) + (z02+z03));
        float z1 = reduce16((z10+z11) + (z12+z13));
        if (g.sub == (t & 15)) {
            out[OUT_REC + g.n0*TM_ + t*M_ + g.m0] = z0;
            out[OUT_REC + g.n1*TM_ + t*M_ + g.m1] = z1;
        }
    }
}

// ---------------------------------------------------------------------------
extern "C" void kernel_launch(void* const* d_in, const int* in_sizes, int n_in,
                              void* d_out, int out_size, void* d_ws, size_t ws_size,
                              hipStream_t stream) {
    const float* X  = (const float*)d_in[0];
    const float* rr = (const float*)d_in[1];
    const float* th = (const float*)d_in[2];
    float* out = (float*)d_out;
    float* ws  = (float*)d_ws;

    // zero conv accumulators + wn accumulator + niter slots (every call)
    hipMemsetAsync((char*)d_ws + WS_ACC*sizeof(float), 0, 4096, stream);
    k_dict  <<<dim3(1),   dim3(256), 0, stream>>>(rr, th, out, ws);
    k_run<0><<<dim3(NBR), dim3(NTR), 0, stream>>>(X, out, ws);
    k_scan  <<<dim3(1),   dim3(64),  0, stream>>>(ws, 0);
    k_fin1  <<<dim3(NBR), dim3(NTR), 0, stream>>>(X, out, ws);
    k_run<1><<<dim3(NBR), dim3(NTR), 0, stream>>>(X, out, ws);
    k_scan  <<<dim3(1),   dim3(64),  0, stream>>>(ws, 1);
    k_fin2  <<<dim3(NBR), dim3(NTR), 0, stream>>>(X, out, ws);
}

// Round 7
// 1793.137 us; speedup vs baseline: 3.5758x; 1.0318x over previous
//
#include <hip/hip_runtime.h>
#include <math.h>

// ---------------- problem constants (fixed by setup_inputs) ----------------
#define N_    256
#define T_    36
#define M_    50
#define P_    80
#define K_    161          // 1 + 2P
#define PADK  192          // K padded to 16*12, pad cols are zero
#define KC    12           // k-elements per lane (16 lanes per column)
#define NBR   800          // run-kernel blocks (2 waves each -> 1600 waves)
#define NTR   128          // 2 waves/block: wave-granular load balance
#define LAM_  0.1f
#define MAXIT 100

#define KM_     (K_*M_)        // 8050
#define TM_     (T_*M_)        // 1800
#define OUT_DIC 2060800        // N*K*M
#define OUT_REC 2066596        // + T*K

// ---- workspace float offsets ----
#define WS_LINV 0
#define WS_D    64             // 36*192 = 6912 floats
#define WS_ACC  8192           // 2 passes * 100 iters * 4 slots = 800 floats
#define WS_WN   9000           // 1 float (sum of wn^2 over pass-1 code)
#define WS_NIT1 9002           // int slot: pass-1 replay count (101 = none)
#define WS_NIT2 9003           // int slot: pass-2 replay count

// ---------------------------------------------------------------------------
// kernel 1: build dictionary (write dic output + padded D to ws) and
// Linv = 1/frob(DtD) using frob(DtD) == frob(D D^T)  (36x36 instead of 161^2)
// ---------------------------------------------------------------------------
__global__ __launch_bounds__(256) void k_dict(const float* __restrict__ rr,
                                              const float* __restrict__ th,
                                              float* __restrict__ out,
                                              float* __restrict__ ws) {
    __shared__ float Dl[T_*PADK];
    const int tid = threadIdx.x;
    for (int e = tid; e < T_*PADK; e += 256) {
        int t = e / PADK, k = e - (e / PADK) * PADK;
        float v = 0.f;
        if (k == 0) v = 1.f;
        else if (k <= P_)      { float r = rr[k-1];     float a = th[k-1]*(float)t;
                                 v = powf(r, (float)t) * cosf(a); }
        else if (k <= 2*P_)    { float r = rr[k-1-P_];  float a = th[k-1-P_]*(float)t;
                                 v = powf(r, (float)t) * sinf(a); }
        Dl[e] = v;
        ws[WS_D + e] = v;
        if (k < K_) out[OUT_DIC + t*K_ + k] = v;
    }
    __syncthreads();
    float loc = 0.f;
    for (int e = tid; e < T_*T_; e += 256) {
        int t1 = e / T_, t2 = e - (e / T_) * T_;
        float s = 0.f;
        for (int k = 0; k < K_; ++k) s = fmaf(Dl[t1*PADK+k], Dl[t2*PADK+k], s);
        loc = fmaf(s, s, loc);
    }
    #pragma unroll
    for (int mm = 1; mm < 64; mm <<= 1) loc += __shfl_xor(loc, mm);
    __shared__ float rb[4];
    if ((tid & 63) == 0) rb[tid >> 6] = loc;
    __syncthreads();
    if (tid == 0) {
        float tot = rb[0] + rb[1] + rb[2] + rb[3];
        ws[WS_LINV] = 1.0f / sqrtf(tot);
    }
}

// ---- DPP-based 16-lane sum (pure VALU, off the LDS pipe) -------------------
template<int CTRL>
__device__ __forceinline__ float dpp_mov(float v) {
    int p = __builtin_amdgcn_update_dpp(0, __float_as_int(v), CTRL, 0xF, 0xF, true);
    return __int_as_float(p);
}
__device__ __forceinline__ float reduce16(float z) {
    z += dpp_mov<0xB1>(z);     // quad_perm [1,0,3,2]  (xor 1)
    z += dpp_mov<0x4E>(z);     // quad_perm [2,3,0,1]  (xor 2)
    z += dpp_mov<0x141>(z);    // row_half_mirror      (other quad)
    z += dpp_mov<0x140>(z);    // row_mirror           (other 8-group)
    return z;
}

// ---------------------------------------------------------------------------
// k_run<PASS>: one reweighting pass, MAXIT iters, record conv norms (4-slot
// spread), write code.  waves_per_eu(1,2): LDS already caps occupancy at
// ~2.5 waves/SIMD, so tell the regalloc not to chase 7 waves/EU by pushing
// state into AGPRs (r6: VGPR=72 + accvgpr traffic ~doubled VALU instrs).
// PASS 0: scalar wl = lam*Linv, state {x,y,b,u}.
// PASS 1: cm/cp = b -/+ wl(x1) precomputed, state {x,y,cm,cp,u}.
// ---------------------------------------------------------------------------
template<int PASS>
__global__ __attribute__((amdgpu_flat_work_group_size(NTR, NTR),
                          amdgpu_waves_per_eu(1, 2)))
void k_run(const float* __restrict__ X,
           float* __restrict__ out,
           float* __restrict__ ws) {
    __shared__ __align__(16) float Dl[T_*PADK];
    const int tid = threadIdx.x;
    for (int e = tid; e < T_*PADK; e += NTR) Dl[e] = ws[WS_D + e];
    const float Linv = ws[WS_LINV];
    __syncthreads();

    const int lane  = tid & 63;
    const int sub   = lane & 15;
    const int gw    = (int)blockIdx.x * (NTR/64) + (tid >> 6);
    const int colb  = gw*8 + (lane >> 4)*2;        // [0, 12800), 2 cols/thread
    const int n0    = colb / M_;
    const int m0    = colb - n0*M_;
    const int n1    = (colb+1) / M_;
    const int m1    = (colb+1) - n1*M_;
    const int kbase = sub * KC;                    // sub>=14 -> pad region
    const float* Y0 = X + n0*TM_ + m0;
    const float* Y1 = X + n1*TM_ + m1;

    float x[2][KC], y[2][KC], cm[2][KC], cp[2][KC];
    // cm/cp usage: PASS==0 -> cm = b (cp unused); PASS==1 -> cm/cp = b -/+ wl
    const float wlc = LAM_ * Linv;

    // ---- b = Linv * (D^T Ycol), stored into cm ----
    #pragma unroll
    for (int j = 0; j < KC; ++j) { cm[0][j] = 0.f; cm[1][j] = 0.f; }
    #pragma unroll 2
    for (int t = 0; t < T_; ++t) {
        float yv0 = Y0[t*M_], yv1 = Y1[t*M_];
        const float4* dp = (const float4*)(Dl + t*PADK + kbase);
        float4 da[3] = {dp[0], dp[1], dp[2]};
        #pragma unroll
        for (int q = 0; q < 3; ++q) {
            cm[0][4*q+0] = fmaf(da[q].x, yv0, cm[0][4*q+0]);
            cm[0][4*q+1] = fmaf(da[q].y, yv0, cm[0][4*q+1]);
            cm[0][4*q+2] = fmaf(da[q].z, yv0, cm[0][4*q+2]);
            cm[0][4*q+3] = fmaf(da[q].w, yv0, cm[0][4*q+3]);
            cm[1][4*q+0] = fmaf(da[q].x, yv1, cm[1][4*q+0]);
            cm[1][4*q+1] = fmaf(da[q].y, yv1, cm[1][4*q+1]);
            cm[1][4*q+2] = fmaf(da[q].z, yv1, cm[1][4*q+2]);
            cm[1][4*q+3] = fmaf(da[q].w, yv1, cm[1][4*q+3]);
        }
    }
    #pragma unroll
    for (int j = 0; j < KC; ++j) { cm[0][j] *= Linv; cm[1][j] *= Linv; }

    if (PASS == 1) {
        // wl = K*lam*Linv/||wn|| * 1/(|x1|+0.01); cm=b-wl, cp=b+wl
        float scale = ((float)K_) * (LAM_ * Linv) / sqrtf(ws[WS_WN]);
        #pragma unroll
        for (int c = 0; c < 2; ++c) {
            const int nn = c ? n1 : n0, mm2 = c ? m1 : m0;
            #pragma unroll
            for (int j = 0; j < KC; ++j) {
                int kg = kbase + j;
                float x1 = (kg < K_) ? out[nn*KM_ + kg*M_ + mm2] : 0.f;
                float wl = scale / (fabsf(x1) + 0.01f);
                float bb = cm[c][j];
                cm[c][j] = bb - wl;
                cp[c][j] = bb + wl;
            }
        }
    }

    float tcur = 1.f;

    auto iterate = [&](float tt) -> float {
        float u[2][KC];
        #pragma unroll
        for (int j = 0; j < KC; ++j) { u[0][j] = 0.f; u[1][j] = 0.f; }
        #pragma unroll 2
        for (int t = 0; t < T_; ++t) {
            const float4* dp = (const float4*)(Dl + t*PADK + kbase);
            float4 da[3] = {dp[0], dp[1], dp[2]};
            float z00=0.f, z01=0.f, z02=0.f, z03=0.f;
            float z10=0.f, z11=0.f, z12=0.f, z13=0.f;
            #pragma unroll
            for (int q = 0; q < 3; ++q) {
                z00 = fmaf(da[q].x, y[0][4*q+0], z00);
                z01 = fmaf(da[q].y, y[0][4*q+1], z01);
                z02 = fmaf(da[q].z, y[0][4*q+2], z02);
                z03 = fmaf(da[q].w, y[0][4*q+3], z03);
                z10 = fmaf(da[q].x, y[1][4*q+0], z10);
                z11 = fmaf(da[q].y, y[1][4*q+1], z11);
                z12 = fmaf(da[q].z, y[1][4*q+2], z12);
                z13 = fmaf(da[q].w, y[1][4*q+3], z13);
            }
            float z0 = reduce16((z00+z01) + (z02+z03));   // 16 lanes hold z_t
            float z1 = reduce16((z10+z11) + (z12+z13));
            #pragma unroll
            for (int q = 0; q < 3; ++q) {
                u[0][4*q+0] = fmaf(da[q].x, z0, u[0][4*q+0]);
                u[0][4*q+1] = fmaf(da[q].y, z0, u[0][4*q+1]);
                u[0][4*q+2] = fmaf(da[q].z, z0, u[0][4*q+2]);
                u[0][4*q+3] = fmaf(da[q].w, z0, u[0][4*q+3]);
                u[1][4*q+0] = fmaf(da[q].x, z1, u[1][4*q+0]);
                u[1][4*q+1] = fmaf(da[q].y, z1, u[1][4*q+1]);
                u[1][4*q+2] = fmaf(da[q].z, z1, u[1][4*q+2]);
                u[1][4*q+3] = fmaf(da[q].w, z1, u[1][4*q+3]);
            }
        }
        float ss = 0.f;
        #pragma unroll
        for (int c = 0; c < 2; ++c) {
            #pragma unroll
            for (int j = 0; j < KC; ++j) {
                float v = fmaf(-Linv, u[c][j], y[c][j]);   // Ay
                float xn;
                if (PASS == 0) {
                    float s = v + cm[c][j];                 // Ay + b
                    xn = fmaxf(0.f, s - wlc) + fminf(0.f, s + wlc);
                } else {
                    xn = fmaxf(0.f, v + cm[c][j]) + fminf(0.f, v + cp[c][j]);
                }
                float d = xn - x[c][j];
                ss      = fmaf(d, d, ss);
                y[c][j] = fmaf(tt, d, xn);
                x[c][j] = xn;
            }
        }
        return ss;
    };

    #pragma unroll
    for (int j = 0; j < KC; ++j) {
        x[0][j] = 0.f; x[1][j] = 0.f; y[0][j] = 0.f; y[1][j] = 0.f;
    }
    float* acc = ws + WS_ACC + PASS*4*MAXIT;
    for (int i = 0; i < MAXIT; ++i) {
        float tnext = 0.5f * (1.f + sqrtf(fmaf(4.f*tcur, tcur, 1.f)));
        float tt = (tcur - 1.f) / tnext;
        tcur = tnext;
        float ss = iterate(tt);
        ss = reduce16(ss);                         // 4 DPP levels (VALU)
        ss += __shfl_xor(ss, 16);
        ss += __shfl_xor(ss, 32);
        if (lane == 0) atomicAdd(acc + i*4 + (gw & 3), ss);   // fire-and-forget
    }

    // ---- write code ----
    #pragma unroll
    for (int j = 0; j < KC; ++j) {
        int kg = kbase + j;
        if (kg < K_) {
            out[n0*KM_ + kg*M_ + m0] = x[0][j];
            out[n1*KM_ + kg*M_ + m1] = x[1][j];
        }
    }
}

// ---------------------------------------------------------------------------
// helpers for the (rarely-executed) replay/finish kernels
// ---------------------------------------------------------------------------
struct Geo { int n0, m0, n1, m1, kbase, sub, lane; };
__device__ __forceinline__ Geo make_geo() {
    Geo g;
    const int tid = threadIdx.x;
    g.lane = tid & 63;
    g.sub  = g.lane & 15;
    const int gw   = (int)blockIdx.x * (NTR/64) + (tid >> 6);
    const int colb = gw*8 + (g.lane >> 4)*2;
    g.n0 = colb / M_;       g.m0 = colb - g.n0*M_;
    g.n1 = (colb+1) / M_;   g.m1 = (colb+1) - g.n1*M_;
    g.kbase = g.sub * KC;
    return g;
}

__device__ __forceinline__ void compute_b(const float* Dl, int kbase, float Linv,
                                          const float* Y0, const float* Y1,
                                          float (&b)[2][KC]) {
    #pragma unroll
    for (int j = 0; j < KC; ++j) { b[0][j] = 0.f; b[1][j] = 0.f; }
    #pragma unroll 2
    for (int t = 0; t < T_; ++t) {
        float yv0 = Y0[t*M_], yv1 = Y1[t*M_];
        const float4* dp = (const float4*)(Dl + t*PADK + kbase);
        float4 da[3] = {dp[0], dp[1], dp[2]};
        #pragma unroll
        for (int q = 0; q < 3; ++q) {
            b[0][4*q+0] = fmaf(da[q].x, yv0, b[0][4*q+0]);
            b[0][4*q+1] = fmaf(da[q].y, yv0, b[0][4*q+1]);
            b[0][4*q+2] = fmaf(da[q].z, yv0, b[0][4*q+2]);
            b[0][4*q+3] = fmaf(da[q].w, yv0, b[0][4*q+3]);
            b[1][4*q+0] = fmaf(da[q].x, yv1, b[1][4*q+0]);
            b[1][4*q+1] = fmaf(da[q].y, yv1, b[1][4*q+1]);
            b[1][4*q+2] = fmaf(da[q].z, yv1, b[1][4*q+2]);
            b[1][4*q+3] = fmaf(da[q].w, yv1, b[1][4*q+3]);
        }
    }
    #pragma unroll
    for (int j = 0; j < KC; ++j) { b[0][j] *= Linv; b[1][j] *= Linv; }
}

// generic FISTA run with per-element cm/cp (used only on replay paths)
__device__ __forceinline__ void run_fista(const float* Dl, int kbase, float Linv,
                                          const float (&cmv)[2][KC],
                                          const float (&cpv)[2][KC],
                                          float (&x)[2][KC], int nit) {
    float y[2][KC];
    #pragma unroll
    for (int j = 0; j < KC; ++j) {
        x[0][j] = 0.f; x[1][j] = 0.f; y[0][j] = 0.f; y[1][j] = 0.f;
    }
    float tcur = 1.f;
    for (int i = 0; i < nit; ++i) {
        float tnext = 0.5f * (1.f + sqrtf(fmaf(4.f*tcur, tcur, 1.f)));
        float tt = (tcur - 1.f) / tnext;
        tcur = tnext;
        float u[2][KC];
        #pragma unroll
        for (int j = 0; j < KC; ++j) { u[0][j] = 0.f; u[1][j] = 0.f; }
        #pragma unroll 2
        for (int t = 0; t < T_; ++t) {
            const float4* dp = (const float4*)(Dl + t*PADK + kbase);
            float4 da[3] = {dp[0], dp[1], dp[2]};
            float z00=0.f, z01=0.f, z02=0.f, z03=0.f;
            float z10=0.f, z11=0.f, z12=0.f, z13=0.f;
            #pragma unroll
            for (int q = 0; q < 3; ++q) {
                z00 = fmaf(da[q].x, y[0][4*q+0], z00);
                z01 = fmaf(da[q].y, y[0][4*q+1], z01);
                z02 = fmaf(da[q].z, y[0][4*q+2], z02);
                z03 = fmaf(da[q].w, y[0][4*q+3], z03);
                z10 = fmaf(da[q].x, y[1][4*q+0], z10);
                z11 = fmaf(da[q].y, y[1][4*q+1], z11);
                z12 = fmaf(da[q].z, y[1][4*q+2], z12);
                z13 = fmaf(da[q].w, y[1][4*q+3], z13);
            }
            float z0 = reduce16((z00+z01) + (z02+z03));
            float z1 = reduce16((z10+z11) + (z12+z13));
            #pragma unroll
            for (int q = 0; q < 3; ++q) {
                u[0][4*q+0] = fmaf(da[q].x, z0, u[0][4*q+0]);
                u[0][4*q+1] = fmaf(da[q].y, z0, u[0][4*q+1]);
                u[0][4*q+2] = fmaf(da[q].z, z0, u[0][4*q+2]);
                u[0][4*q+3] = fmaf(da[q].w, z0, u[0][4*q+3]);
                u[1][4*q+0] = fmaf(da[q].x, z1, u[1][4*q+0]);
                u[1][4*q+1] = fmaf(da[q].y, z1, u[1][4*q+1]);
                u[1][4*q+2] = fmaf(da[q].z, z1, u[1][4*q+2]);
                u[1][4*q+3] = fmaf(da[q].w, z1, u[1][4*q+3]);
            }
        }
        #pragma unroll
        for (int c = 0; c < 2; ++c) {
            #pragma unroll
            for (int j = 0; j < KC; ++j) {
                float v = fmaf(-Linv, u[c][j], y[c][j]);
                float xn = fmaxf(0.f, v + cmv[c][j]) + fminf(0.f, v + cpv[c][j]);
                float d = xn - x[c][j];
                y[c][j] = fmaf(tt, d, xn);
                x[c][j] = xn;
            }
        }
    }
}

__device__ __forceinline__ void write_code_g(const Geo& g, const float (&x)[2][KC],
                                             float* out) {
    #pragma unroll
    for (int j = 0; j < KC; ++j) {
        int kg = g.kbase + j;
        if (kg < K_) {
            out[g.n0*KM_ + kg*M_ + g.m0] = x[0][j];
            out[g.n1*KM_ + kg*M_ + g.m1] = x[1][j];
        }
    }
}
__device__ __forceinline__ void load_code_g(const Geo& g, float (&x)[2][KC],
                                            const float* out) {
    #pragma unroll
    for (int j = 0; j < KC; ++j) {
        int kg = g.kbase + j;
        x[0][j] = (kg < K_) ? out[g.n0*KM_ + kg*M_ + g.m0] : 0.f;
        x[1][j] = (kg < K_) ? out[g.n1*KM_ + kg*M_ + g.m1] : 0.f;
    }
}

// ---------------------------------------------------------------------------
// k_scan: find first iter with global ||dx||^2 < (tol*K)^2 (4 slots per iter)
// ---------------------------------------------------------------------------
__global__ void k_scan(float* __restrict__ ws, int pass) {
    const float THR2 = (1e-5f * (float)K_) * (1e-5f * (float)K_);
    int lane = threadIdx.x;
    const float* acc = ws + WS_ACC + pass*4*MAXIT;
    int best = MAXIT + 1;
    for (int i = lane; i < MAXIT; i += 64) {
        float a = (acc[i*4] + acc[i*4+1]) + (acc[i*4+2] + acc[i*4+3]);
        if (a < THR2) best = min(best, i + 1);
    }
    #pragma unroll
    for (int mm = 1; mm < 64; mm <<= 1) best = min(best, __shfl_xor(best, mm));
    if (lane == 0) ((int*)ws)[pass == 0 ? WS_NIT1 : WS_NIT2] = best;
}

// ---------------------------------------------------------------------------
// k_fin1: if pass-1 converged early, replay nit1 iters and rewrite code;
// then accumulate ||wn||^2 into WS_WN. (Expected: no replay -> cheap.)
// ---------------------------------------------------------------------------
__global__ __launch_bounds__(NTR, 1) void k_fin1(const float* __restrict__ X,
                                                 float* __restrict__ out,
                                                 float* __restrict__ ws) {
    __shared__ __align__(16) float Dl[T_*PADK];
    for (int e = threadIdx.x; e < T_*PADK; e += NTR) Dl[e] = ws[WS_D + e];
    const float Linv = ws[WS_LINV];
    __syncthreads();

    Geo g = make_geo();
    const int nit1 = ((const int*)ws)[WS_NIT1];
    float x[2][KC];

    if (nit1 <= MAXIT) {
        float b[2][KC], cmv[2][KC], cpv[2][KC];
        compute_b(Dl, g.kbase, Linv, X + g.n0*TM_ + g.m0, X + g.n1*TM_ + g.m1, b);
        const float wlc = LAM_ * Linv;
        #pragma unroll
        for (int c = 0; c < 2; ++c)
            #pragma unroll
            for (int j = 0; j < KC; ++j) { cmv[c][j] = b[c][j] - wlc;
                                           cpv[c][j] = b[c][j] + wlc; }
        run_fista(Dl, g.kbase, Linv, cmv, cpv, x, nit1);
        write_code_g(g, x, out);
    } else {
        load_code_g(g, x, out);
    }

    float loc = 0.f;
    #pragma unroll
    for (int c = 0; c < 2; ++c)
        #pragma unroll
        for (int j = 0; j < KC; ++j) {
            if (g.kbase + j < K_) {
                float wn = 1.0f / (fabsf(x[c][j]) + 0.01f);
                loc = fmaf(wn, wn, loc);
            }
        }
    #pragma unroll
    for (int mm = 1; mm < 64; mm <<= 1) loc += __shfl_xor(loc, mm);
    if (g.lane == 0) atomicAdd(ws + WS_WN, loc);
}

// ---------------------------------------------------------------------------
// k_fin2: if pass-2 converged early, re-derive pass-1 x, recompute weights,
// replay nit2 iters, rewrite code. Always write reconst from final code.
// ---------------------------------------------------------------------------
__global__ __launch_bounds__(NTR, 1) void k_fin2(const float* __restrict__ X,
                                                 float* __restrict__ out,
                                                 float* __restrict__ ws) {
    __shared__ __align__(16) float Dl[T_*PADK];
    for (int e = threadIdx.x; e < T_*PADK; e += NTR) Dl[e] = ws[WS_D + e];
    const float Linv = ws[WS_LINV];
    __syncthreads();

    Geo g = make_geo();
    const int nit1 = ((const int*)ws)[WS_NIT1];
    const int nit2 = ((const int*)ws)[WS_NIT2];
    float x[2][KC];

    if (nit2 <= MAXIT) {
        float b[2][KC], cmv[2][KC], cpv[2][KC];
        compute_b(Dl, g.kbase, Linv, X + g.n0*TM_ + g.m0, X + g.n1*TM_ + g.m1, b);
        const float wlc = LAM_ * Linv;
        #pragma unroll
        for (int c = 0; c < 2; ++c)
            #pragma unroll
            for (int j = 0; j < KC; ++j) { cmv[c][j] = b[c][j] - wlc;
                                           cpv[c][j] = b[c][j] + wlc; }
        int nrep1 = nit1 <= MAXIT ? nit1 : MAXIT;
        run_fista(Dl, g.kbase, Linv, cmv, cpv, x, nrep1);
        float scale = ((float)K_) * (LAM_ * Linv) / sqrtf(ws[WS_WN]);
        #pragma unroll
        for (int c = 0; c < 2; ++c)
            #pragma unroll
            for (int j = 0; j < KC; ++j) {
                float wl = scale / (fabsf(x[c][j]) + 0.01f);
                cmv[c][j] = b[c][j] - wl;
                cpv[c][j] = b[c][j] + wl;
            }
        run_fista(Dl, g.kbase, Linv, cmv, cpv, x, nit2);
        write_code_g(g, x, out);
    } else {
        load_code_g(g, x, out);
    }

    // ---- reconst = D @ code ----
    #pragma unroll 2
    for (int t = 0; t < T_; ++t) {
        const float4* dp = (const float4*)(Dl + t*PADK + g.kbase);
        float4 da[3] = {dp[0], dp[1], dp[2]};
        float z00=0.f, z01=0.f, z02=0.f, z03=0.f;
        float z10=0.f, z11=0.f, z12=0.f, z13=0.f;
        #pragma unroll
        for (int q = 0; q < 3; ++q) {
            z00 = fmaf(da[q].x, x[0][4*q+0], z00);
            z01 = fmaf(da[q].y, x[0][4*q+1], z01);
            z02 = fmaf(da[q].z, x[0][4*q+2], z02);
            z03 = fmaf(da[q].w, x[0][4*q+3], z03);
            z10 = fmaf(da[q].x, x[1][4*q+0], z10);
            z11 = fmaf(da[q].y, x[1][4*q+1], z11);
            z12 = fmaf(da[q].z, x[1][4*q+2], z12);
            z13 = fmaf(da[q].w, x[1][4*q+3], z13);
        }
        float z0 = reduce16((z00+z01) + (z02+z03));
        float z1 = reduce16((z10+z11) + (z12+z13));
        if (g.sub == (t & 15)) {
            out[OUT_REC + g.n0*TM_ + t*M_ + g.m0] = z0;
            out[OUT_REC + g.n1*TM_ + t*M_ + g.m1] = z1;
        }
    }
}

// ---------------------------------------------------------------------------
extern "C" void kernel_launch(void* const* d_in, const int* in_sizes, int n_in,
                              void* d_out, int out_size, void* d_ws, size_t ws_size,
                              hipStream_t stream) {
    const float* X  = (const float*)d_in[0];
    const float* rr = (const float*)d_in[1];
    const float* th = (const float*)d_in[2];
    float* out = (float*)d_out;
    float* ws  = (float*)d_ws;

    // zero conv accumulators + wn accumulator + niter slots (every call)
    hipMemsetAsync((char*)d_ws + WS_ACC*sizeof(float), 0, 4096, stream);
    k_dict  <<<dim3(1),   dim3(256), 0, stream>>>(rr, th, out, ws);
    k_run<0><<<dim3(NBR), dim3(NTR), 0, stream>>>(X, out, ws);
    k_scan  <<<dim3(1),   dim3(64),  0, stream>>>(ws, 0);
    k_fin1  <<<dim3(NBR), dim3(NTR), 0, stream>>>(X, out, ws);
    k_run<1><<<dim3(NBR), dim3(NTR), 0, stream>>>(X, out, ws);
    k_scan  <<<dim3(1),   dim3(64),  0, stream>>>(ws, 1);
    k_fin2  <<<dim3(NBR), dim3(NTR), 0, stream>>>(X, out, ws);
}